// Round 1
// baseline (1208.428 us; speedup 1.0000x reference)
//
#include <hip/hip_runtime.h>

// B=32, S=1024, H=1024, E=512, V=32000
// d_out layout: pred[32*32000] | h_new[32768] | c_new[32768] | weights[32768]

typedef __attribute__((ext_vector_type(8))) short bf16x8;
typedef __attribute__((ext_vector_type(4))) float f32x4;

__device__ __forceinline__ unsigned short f2bf(float f) {
  unsigned int u = __float_as_uint(f);
  u += 0x7fffu + ((u >> 16) & 1u);   // RNE
  return (unsigned short)(u >> 16);
}

__device__ __forceinline__ uint4 pack8(float4 a, float4 b) {
  union { unsigned short u[8]; uint4 v; } p;
  p.u[0] = f2bf(a.x); p.u[1] = f2bf(a.y); p.u[2] = f2bf(a.z); p.u[3] = f2bf(a.w);
  p.u[4] = f2bf(b.x); p.u[5] = f2bf(b.y); p.u[6] = f2bf(b.z); p.u[7] = f2bf(b.w);
  return p.v;
}

// ---------------- K0: init (zero scores, bias-init gates & pred, embedding gather) -------------
__global__ __launch_bounds__(256) void init_kernel(
    float* __restrict__ scores, float* __restrict__ gates, float* __restrict__ pred,
    float* __restrict__ lstm_in, const int* __restrict__ x, const float* __restrict__ emb,
    const float* __restrict__ b_ih, const float* __restrict__ b_hh,
    const float* __restrict__ fc_b)
{
  int idx = blockIdx.x * 256 + threadIdx.x;
  if (idx < 32768) { scores[idx] = 0.f; return; }
  idx -= 32768;
  if (idx < 131072) { gates[idx] = b_ih[idx & 4095] + b_hh[idx & 4095]; return; }
  idx -= 131072;
  if (idx < 1024000) { pred[idx] = fc_b[idx % 32000]; return; }
  idx -= 1024000;
  if (idx < 16384) {
    int b = idx >> 9, e = idx & 511;
    lstm_in[b * 2560 + e] = emb[(size_t)x[b] * 512 + e];
  }
}

// ---------------- K1: hb[b][h] = attn_b[h] + sum_k hidden[b][k]*attn_W[h][k] ------------------
// one wave per h, 4 waves/block, grid 256
__global__ __launch_bounds__(256) void hb_kernel(
    const float* __restrict__ hidden, const float* __restrict__ attn_W,
    const float* __restrict__ attn_b, float* __restrict__ hb)
{
  const int lane = threadIdx.x & 63;
  const int h = blockIdx.x * 4 + (threadIdx.x >> 6);
  const float4* wp = (const float4*)(attn_W + (size_t)h * 3072 + lane * 16);
  float4 w0 = wp[0], w1 = wp[1], w2 = wp[2], w3 = wp[3];
  float bias = attn_b[h];
  for (int b = 0; b < 32; ++b) {
    const float4* hp = (const float4*)(hidden + b * 1024 + lane * 16);
    float4 h0 = hp[0], h1 = hp[1], h2 = hp[2], h3 = hp[3];
    float p = w0.x*h0.x + w0.y*h0.y + w0.z*h0.z + w0.w*h0.w
            + w1.x*h1.x + w1.y*h1.y + w1.z*h1.z + w1.w*h1.w
            + w2.x*h2.x + w2.y*h2.y + w2.z*h2.z + w2.w*h2.w
            + w3.x*h3.x + w3.y*h3.y + w3.z*h3.z + w3.w*h3.w;
    #pragma unroll
    for (int d = 1; d < 64; d <<= 1) p += __shfl_xor(p, d);
    if (lane == 0) hb[b * 1024 + h] = p + bias;
  }
}

// ---------------- K2: energy GEMM + tanh + dot(v) epilogue -> scores partials -----------------
// M=32768 (m=b*1024+s), N=1024 (h), K=2048. A=enc fp32->bf16, B^T=attn_W[:,1024:3072].
// Block tile 128x128, 4 waves in 2x2 quadrants of 64x64, mfma_f32_16x16x32_bf16.
__global__ __launch_bounds__(256) void energy_kernel(
    const float* __restrict__ enc, const float* __restrict__ attn_W,
    const float* __restrict__ hb, const float* __restrict__ v_W,
    float* __restrict__ scores)
{
  __shared__ short Al[128][40];   // +8 bf16 pad: keeps 16B alignment, 2-way banks (free)
  __shared__ short Bl[128][40];
  const int tid = threadIdx.x;
  const int lane = tid & 63, wave = tid >> 6;
  const int m0 = blockIdx.x * 128;
  const int n0 = blockIdx.y * 128;
  const int b  = m0 >> 10;                 // 128 | 1024 so b is block-uniform
  const int wm = (wave >> 1) * 64, wn = (wave & 1) * 64;

  f32x4 acc[4][4];
  #pragma unroll
  for (int i = 0; i < 4; ++i)
    #pragma unroll
    for (int j = 0; j < 4; ++j) acc[i][j] = (f32x4){0.f, 0.f, 0.f, 0.f};

  const int srow = tid >> 1;               // 128 rows, 2 threads/row
  const int scol = (tid & 1) * 16;         // 16 floats each
  const float* aptr = enc    + (size_t)(m0 + srow) * 2048 + scol;
  const float* bptr = attn_W + (size_t)(n0 + srow) * 3072 + 1024 + scol;

  const int fl = lane & 15, fq = (lane >> 4) * 8;

  for (int k0 = 0; k0 < 2048; k0 += 32) {
    const float4* a4 = (const float4*)(aptr + k0);
    float4 fa0 = a4[0], fa1 = a4[1], fa2 = a4[2], fa3 = a4[3];
    const float4* b4 = (const float4*)(bptr + k0);
    float4 fb0 = b4[0], fb1 = b4[1], fb2 = b4[2], fb3 = b4[3];
    *(uint4*)&Al[srow][scol]     = pack8(fa0, fa1);
    *(uint4*)&Al[srow][scol + 8] = pack8(fa2, fa3);
    *(uint4*)&Bl[srow][scol]     = pack8(fb0, fb1);
    *(uint4*)&Bl[srow][scol + 8] = pack8(fb2, fb3);
    __syncthreads();

    bf16x8 af[4], bf[4];
    #pragma unroll
    for (int i = 0; i < 4; ++i) af[i] = *(const bf16x8*)&Al[wm + i * 16 + fl][fq];
    #pragma unroll
    for (int j = 0; j < 4; ++j) bf[j] = *(const bf16x8*)&Bl[wn + j * 16 + fl][fq];
    #pragma unroll
    for (int i = 0; i < 4; ++i)
      #pragma unroll
      for (int j = 0; j < 4; ++j)
        acc[i][j] = __builtin_amdgcn_mfma_f32_16x16x32_bf16(af[i], bf[j], acc[i][j], 0, 0, 0);
    __syncthreads();
  }

  // epilogue: e = tanh(acc + hb[b][col]); rowsum += v[col]*e ; reduce over 16 lanes ; atomic
  float rsum[4][4];
  #pragma unroll
  for (int i = 0; i < 4; ++i)
    #pragma unroll
    for (int r = 0; r < 4; ++r) rsum[i][r] = 0.f;

  const int col_base = n0 + wn + (lane & 15);
  #pragma unroll
  for (int j = 0; j < 4; ++j) {
    int col = col_base + j * 16;
    float hbv = hb[b * 1024 + col];
    float vv  = v_W[col];
    #pragma unroll
    for (int i = 0; i < 4; ++i)
      #pragma unroll
      for (int r = 0; r < 4; ++r)
        rsum[i][r] += vv * tanhf(acc[i][j][r] + hbv);
  }
  #pragma unroll
  for (int i = 0; i < 4; ++i)
    #pragma unroll
    for (int r = 0; r < 4; ++r) {
      float v = rsum[i][r];
      v += __shfl_xor(v, 1); v += __shfl_xor(v, 2);
      v += __shfl_xor(v, 4); v += __shfl_xor(v, 8);
      rsum[i][r] = v;
    }
  if ((lane & 15) == 0) {
    const int q = lane >> 4;
    const int sbase = (m0 & 1023) + wm;
    #pragma unroll
    for (int i = 0; i < 4; ++i)
      #pragma unroll
      for (int r = 0; r < 4; ++r)
        atomicAdd(&scores[b * 1024 + sbase + i * 16 + q * 4 + r], rsum[i][r]);
  }
}

// ---------------- K3: softmax over S per b -> weights (into d_out) ----------------------------
__global__ __launch_bounds__(256) void softmax_kernel(
    const float* __restrict__ scores, float* __restrict__ wout)
{
  __shared__ float red[8];
  const int b = blockIdx.x, tid = threadIdx.x;
  const int lane = tid & 63, wave = tid >> 6;
  float v[4];
  #pragma unroll
  for (int r = 0; r < 4; ++r) v[r] = scores[b * 1024 + r * 256 + tid];
  float m = fmaxf(fmaxf(v[0], v[1]), fmaxf(v[2], v[3]));
  #pragma unroll
  for (int d = 1; d < 64; d <<= 1) m = fmaxf(m, __shfl_xor(m, d));
  if (lane == 0) red[wave] = m;
  __syncthreads();
  float M = fmaxf(fmaxf(red[0], red[1]), fmaxf(red[2], red[3]));
  float s = 0.f;
  #pragma unroll
  for (int r = 0; r < 4; ++r) { v[r] = expf(v[r] - M); s += v[r]; }
  #pragma unroll
  for (int d = 1; d < 64; d <<= 1) s += __shfl_xor(s, d);
  __syncthreads();
  if (lane == 0) red[4 + wave] = s;
  __syncthreads();
  float inv = 1.f / (red[4] + red[5] + red[6] + red[7]);
  #pragma unroll
  for (int r = 0; r < 4; ++r) wout[b * 1024 + r * 256 + tid] = v[r] * inv;
}

// ---------------- K4: context[b][d] = sum_s w[b][s]*enc[b][s][d] -> lstm_in[b][512+d] ---------
__global__ __launch_bounds__(256) void context_kernel(
    const float* __restrict__ enc, const float* __restrict__ wts, float* __restrict__ lstm_in)
{
  __shared__ float wl[1024];
  const int tid = threadIdx.x;
  const int b = blockIdx.y;
  const int col = blockIdx.x * 256 + tid;
  #pragma unroll
  for (int r = 0; r < 4; ++r) wl[r * 256 + tid] = wts[b * 1024 + r * 256 + tid];
  __syncthreads();
  const float* ep = enc + (size_t)b * (1024 * 2048) + col;
  float a0 = 0.f, a1 = 0.f, a2 = 0.f, a3 = 0.f;
  for (int s = 0; s < 1024; s += 8) {
    a0 += wl[s + 0] * ep[(size_t)(s + 0) * 2048];
    a1 += wl[s + 1] * ep[(size_t)(s + 1) * 2048];
    a2 += wl[s + 2] * ep[(size_t)(s + 2) * 2048];
    a3 += wl[s + 3] * ep[(size_t)(s + 3) * 2048];
    a0 += wl[s + 4] * ep[(size_t)(s + 4) * 2048];
    a1 += wl[s + 5] * ep[(size_t)(s + 5) * 2048];
    a2 += wl[s + 6] * ep[(size_t)(s + 6) * 2048];
    a3 += wl[s + 7] * ep[(size_t)(s + 7) * 2048];
  }
  lstm_in[b * 2560 + 512 + col] = (a0 + a1) + (a2 + a3);
}

// ---------------- skinny GEMM: out[b][j] += sum_{k in chunk} W[j][k] * X[b][k], B=32 ----------
// thread-per-j (256 j per block), k-split over blockIdx.y with atomic accumulate.
__global__ __launch_bounds__(256) void skinny_gemm(
    const float* __restrict__ W, const float* __restrict__ X, float* __restrict__ out,
    int K, int Kc, int ldx, int ldo)
{
  __shared__ float Wl[256][33];
  const int tid = threadIdx.x;
  const int j0 = blockIdx.x * 256;
  const int k0 = blockIdx.y * Kc;
  float acc[32];
  #pragma unroll
  for (int b = 0; b < 32; ++b) acc[b] = 0.f;

  for (int kc = k0; kc < k0 + Kc; kc += 32) {
    __syncthreads();
    #pragma unroll
    for (int q = 0; q < 8; ++q) {
      int row = q * 32 + (tid >> 3);
      int col = (tid & 7) * 4;
      float4 v = *(const float4*)(W + (size_t)(j0 + row) * K + kc + col);
      Wl[row][col + 0] = v.x; Wl[row][col + 1] = v.y;
      Wl[row][col + 2] = v.z; Wl[row][col + 3] = v.w;
    }
    __syncthreads();
    float wreg[32];
    #pragma unroll
    for (int q = 0; q < 32; ++q) wreg[q] = Wl[tid][q];
    #pragma unroll
    for (int b = 0; b < 32; ++b) {
      const float* xp = X + b * ldx + kc;   // wave-uniform -> scalar loads
      float s = 0.f;
      #pragma unroll
      for (int q = 0; q < 32; ++q) s += wreg[q] * xp[q];
      acc[b] += s;
    }
  }
  const int j = j0 + tid;
  #pragma unroll
  for (int b = 0; b < 32; ++b) atomicAdd(&out[(size_t)b * ldo + j], acc[b]);
}

// ---------------- K6: LSTM cell elementwise --------------------------------------------------
__global__ __launch_bounds__(256) void cell_kernel(
    const float* __restrict__ gates, const float* __restrict__ cell_in,
    float* __restrict__ out_h, float* __restrict__ out_c)
{
  const int idx = blockIdx.x * 256 + threadIdx.x;   // 32768
  const int b = idx >> 10, h = idx & 1023;
  const float* g = gates + b * 4096;
  float ig = g[h], fg = g[1024 + h], gg = g[2048 + h], og = g[3072 + h];
  float c = cell_in[idx];
  float si = 1.f / (1.f + expf(-ig));
  float sf = 1.f / (1.f + expf(-fg));
  float so = 1.f / (1.f + expf(-og));
  float cn = sf * c + si * tanhf(gg);
  float hn = so * tanhf(cn);
  out_c[idx] = cn;
  out_h[idx] = hn;
}

extern "C" void kernel_launch(void* const* d_in, const int* in_sizes, int n_in,
                              void* d_out, int out_size, void* d_ws, size_t ws_size,
                              hipStream_t stream) {
  const int*   x       = (const int*)  d_in[0];
  const float* hidden  = (const float*)d_in[1];
  const float* cell    = (const float*)d_in[2];
  const float* enc     = (const float*)d_in[3];
  const float* emb     = (const float*)d_in[4];
  const float* attn_W  = (const float*)d_in[5];
  const float* attn_b  = (const float*)d_in[6];
  const float* v_W     = (const float*)d_in[7];
  const float* W_ih    = (const float*)d_in[8];
  const float* W_hh    = (const float*)d_in[9];
  const float* b_ih    = (const float*)d_in[10];
  const float* b_hh    = (const float*)d_in[11];
  const float* fc_W    = (const float*)d_in[12];
  const float* fc_b    = (const float*)d_in[13];

  float* out   = (float*)d_out;
  float* pred  = out;                 // 32*32000
  float* out_h = out + 1024000;       // 32768
  float* out_c = out + 1056768;       // 32768
  float* out_w = out + 1089536;       // 32768

  float* ws      = (float*)d_ws;
  float* scores  = ws;                // 32768
  float* hb      = ws + 32768;        // 32768
  float* lstm_in = ws + 65536;        // 32*2560
  float* gates   = ws + 147456;       // 32*4096

  init_kernel<<<4704, 256, 0, stream>>>(scores, gates, pred, lstm_in, x, emb, b_ih, b_hh, fc_b);
  hb_kernel<<<256, 256, 0, stream>>>(hidden, attn_W, attn_b, hb);
  energy_kernel<<<dim3(256, 8), 256, 0, stream>>>(enc, attn_W, hb, v_W, scores);
  softmax_kernel<<<32, 256, 0, stream>>>(scores, out_w);
  context_kernel<<<dim3(8, 32), 256, 0, stream>>>(enc, out_w, lstm_in);
  skinny_gemm<<<dim3(16, 16), 256, 0, stream>>>(W_ih, lstm_in, gates, 2560, 160, 2560, 4096);
  skinny_gemm<<<dim3(16, 8), 256, 0, stream>>>(W_hh, hidden, gates, 1024, 128, 1024, 4096);
  cell_kernel<<<128, 256, 0, stream>>>(gates, cell, out_h, out_c);
  skinny_gemm<<<dim3(125, 2), 256, 0, stream>>>(fc_W, out_h, pred, 1024, 512, 1024, 32000);
}

// Round 2
// 1059.710 us; speedup vs baseline: 1.1403x; 1.1403x over previous
//
#include <hip/hip_runtime.h>

// B=32, S=1024, H=1024, E=512, V=32000
// d_out layout: pred[32*32000] | h_new[32768] | c_new[32768] | weights[32768]
// ws layout (floats): scores@0 | hb@32768 | lstm_in@65536 (32x2560) | gates@147456 (32x4096)
// then (fast path, byte offset 1114112): Ac bf16[32768][2048] | Bc bf16[1024][2048]

typedef __attribute__((ext_vector_type(8))) short bf16x8;
typedef __attribute__((ext_vector_type(4))) float f32x4;

__device__ __forceinline__ unsigned short f2bf(float f) {
  unsigned int u = __float_as_uint(f);
  u += 0x7fffu + ((u >> 16) & 1u);   // RNE
  return (unsigned short)(u >> 16);
}

__device__ __forceinline__ uint4 pack8(float4 a, float4 b) {
  union { unsigned short u[8]; uint4 v; } p;
  p.u[0] = f2bf(a.x); p.u[1] = f2bf(a.y); p.u[2] = f2bf(a.z); p.u[3] = f2bf(a.w);
  p.u[4] = f2bf(b.x); p.u[5] = f2bf(b.y); p.u[6] = f2bf(b.z); p.u[7] = f2bf(b.w);
  return p.v;
}

__device__ __forceinline__ void gld16(const void* g, void* l) {
  auto gp = reinterpret_cast<const __attribute__((address_space(1))) unsigned int*>(
      reinterpret_cast<uintptr_t>(g));
  auto lp = reinterpret_cast<__attribute__((address_space(3))) unsigned int*>(
      reinterpret_cast<uintptr_t>(l));
  __builtin_amdgcn_global_load_lds(gp, lp, 16, 0, 0);
}

// ---------------- K0: init (zero scores & lstm ctx, bias-init gates & pred, emb gather) -------
__global__ __launch_bounds__(256) void init_kernel(
    float* __restrict__ scores, float* __restrict__ gates, float* __restrict__ pred,
    float* __restrict__ lstm_in, const int* __restrict__ x, const float* __restrict__ emb,
    const float* __restrict__ b_ih, const float* __restrict__ b_hh,
    const float* __restrict__ fc_b)
{
  int idx = blockIdx.x * 256 + threadIdx.x;
  if (idx < 32768) { scores[idx] = 0.f; return; }
  idx -= 32768;
  if (idx < 131072) { gates[idx] = b_ih[idx & 4095] + b_hh[idx & 4095]; return; }
  idx -= 131072;
  if (idx < 1024000) { pred[idx] = fc_b[idx % 32000]; return; }
  idx -= 1024000;
  if (idx < 16384) {
    int b = idx >> 9, e = idx & 511;
    lstm_in[b * 2560 + e] = emb[(size_t)x[b] * 512 + e];
    return;
  }
  idx -= 16384;
  if (idx < 65536) {
    int b = idx >> 11, d = idx & 2047;
    lstm_in[b * 2560 + 512 + d] = 0.f;
  }
}

// ---------------- convert: enc fp32 -> Ac bf16 ; attn_W[:,1024:3072] -> Bc bf16 ---------------
__global__ __launch_bounds__(256) void convert_kernel(
    const float* __restrict__ enc, const float* __restrict__ attn_W,
    short* __restrict__ Ac, short* __restrict__ Bc)
{
  if (blockIdx.x < 32768) {
    size_t idx = (size_t)blockIdx.x * 256 + threadIdx.x;     // 8-elem chunk
    const float4* p = (const float4*)enc + idx * 2;
    float4 a = p[0], b = p[1];
    *(uint4*)(Ac + idx * 8) = pack8(a, b);
  } else {
    int cc = (blockIdx.x - 32768) * 256 + threadIdx.x;       // 0..262143
    int r = cc >> 8, c8 = (cc & 255) * 8;
    const float4* p = (const float4*)(attn_W + (size_t)r * 3072 + 1024 + c8);
    *(uint4*)(Bc + (size_t)r * 2048 + c8) = pack8(p[0], p[1]);
  }
}

// ---------------- K1: hb[b][h] = attn_b[h] + sum_k hidden[b][k]*attn_W[h][k] ------------------
__global__ __launch_bounds__(256) void hb_kernel(
    const float* __restrict__ hidden, const float* __restrict__ attn_W,
    const float* __restrict__ attn_b, float* __restrict__ hb)
{
  const int lane = threadIdx.x & 63;
  const int h = blockIdx.x * 4 + (threadIdx.x >> 6);
  const float4* wp = (const float4*)(attn_W + (size_t)h * 3072 + lane * 16);
  float4 w0 = wp[0], w1 = wp[1], w2 = wp[2], w3 = wp[3];
  float bias = attn_b[h];
  for (int b = 0; b < 32; ++b) {
    const float4* hp = (const float4*)(hidden + b * 1024 + lane * 16);
    float4 h0 = hp[0], h1 = hp[1], h2 = hp[2], h3 = hp[3];
    float p = w0.x*h0.x + w0.y*h0.y + w0.z*h0.z + w0.w*h0.w
            + w1.x*h1.x + w1.y*h1.y + w1.z*h1.z + w1.w*h1.w
            + w2.x*h2.x + w2.y*h2.y + w2.z*h2.z + w2.w*h2.w
            + w3.x*h3.x + w3.y*h3.y + w3.z*h3.z + w3.w*h3.w;
    #pragma unroll
    for (int d = 1; d < 64; d <<= 1) p += __shfl_xor(p, d);
    if (lane == 0) hb[b * 1024 + h] = p + bias;
  }
}

// ---------------- K2 fast: energy GEMM (bf16 in, global_load_lds, BK=64) ----------------------
// M=32768, N=1024, K=2048. 128x128 block tile, 4 waves 2x2 quadrants, mfma 16x16x32.
// LDS tiles unpadded [128][64] bf16; 16B chunks XOR-swizzled via the GLOBAL source address
// (LDS dest is wave-uniform base + lane*16, so permutation must ride on the gather side).
__global__ __launch_bounds__(256) void energy2_kernel(
    const short* __restrict__ Ac, const short* __restrict__ Bc,
    const float* __restrict__ hb, const float* __restrict__ v_W,
    float* __restrict__ scores)
{
  __shared__ __align__(16) short Al[128 * 64];
  __shared__ __align__(16) short Bl[128 * 64];
  const int tid = threadIdx.x;
  const int lane = tid & 63, wave = tid >> 6;
  const int m0 = blockIdx.x * 128;
  const int n0 = blockIdx.y * 128;
  const int b  = m0 >> 10;
  const int wm = (wave >> 1) * 64, wn = (wave & 1) * 64;

  f32x4 acc[4][4];
  #pragma unroll
  for (int i = 0; i < 4; ++i)
    #pragma unroll
    for (int j = 0; j < 4; ++j) acc[i][j] = (f32x4){0.f, 0.f, 0.f, 0.f};

  // staging: 4 issues of 16B per thread per tile; LDS chunk L = i*256+tid;
  // row r=L>>3, pos p=L&7 holds global chunk kc = p ^ (r&7)
  const short* ga[4]; const short* gb[4];
  short* la[4]; short* lb[4];
  #pragma unroll
  for (int i = 0; i < 4; ++i) {
    int L = i * 256 + tid;
    int r = L >> 3, p = L & 7;
    int kc = p ^ (r & 7);
    ga[i] = Ac + (size_t)(m0 + r) * 2048 + kc * 8;
    gb[i] = Bc + (size_t)(n0 + r) * 2048 + kc * 8;
    la[i] = Al + (size_t)(i * 256 + (tid & ~63)) * 8;   // wave-uniform
    lb[i] = Bl + (size_t)(i * 256 + (tid & ~63)) * 8;
  }

  const int fl = lane & 15, q = lane >> 4;   // fragment row / k-quad (8 bf16)

  for (int k0 = 0; k0 < 2048; k0 += 64) {
    #pragma unroll
    for (int i = 0; i < 4; ++i) {
      gld16(ga[i], la[i]);
      gld16(gb[i], lb[i]);
      ga[i] += 64; gb[i] += 64;
    }
    __syncthreads();   // drains vmcnt
    #pragma unroll
    for (int s = 0; s < 2; ++s) {
      bf16x8 af[4], bf[4];
      const int c = s * 4 + q;
      #pragma unroll
      for (int i = 0; i < 4; ++i) {
        int ra = wm + i * 16 + fl;
        af[i] = *(const bf16x8*)&Al[ra * 64 + ((c ^ (ra & 7)) * 8)];
        int rb = wn + i * 16 + fl;
        bf[i] = *(const bf16x8*)&Bl[rb * 64 + ((c ^ (rb & 7)) * 8)];
      }
      #pragma unroll
      for (int i = 0; i < 4; ++i)
        #pragma unroll
        for (int j = 0; j < 4; ++j)
          acc[i][j] = __builtin_amdgcn_mfma_f32_16x16x32_bf16(af[i], bf[j], acc[i][j], 0, 0, 0);
    }
    __syncthreads();
  }

  // epilogue: scores[b][s-row] += sum_col v[col]*tanh(acc+hb[b][col])
  float rsum[4][4];
  #pragma unroll
  for (int i = 0; i < 4; ++i)
    #pragma unroll
    for (int r = 0; r < 4; ++r) rsum[i][r] = 0.f;

  const int col_base = n0 + wn + fl;
  #pragma unroll
  for (int j = 0; j < 4; ++j) {
    int col = col_base + j * 16;
    float hbv = hb[b * 1024 + col];
    float vv  = v_W[col];
    #pragma unroll
    for (int i = 0; i < 4; ++i)
      #pragma unroll
      for (int r = 0; r < 4; ++r)
        rsum[i][r] += vv * tanhf(acc[i][j][r] + hbv);
  }
  #pragma unroll
  for (int i = 0; i < 4; ++i)
    #pragma unroll
    for (int r = 0; r < 4; ++r) {
      float v = rsum[i][r];
      v += __shfl_xor(v, 1); v += __shfl_xor(v, 2);
      v += __shfl_xor(v, 4); v += __shfl_xor(v, 8);
      rsum[i][r] = v;
    }
  if (fl == 0) {
    const int sbase = (m0 & 1023) + wm;
    #pragma unroll
    for (int i = 0; i < 4; ++i)
      #pragma unroll
      for (int r = 0; r < 4; ++r)
        atomicAdd(&scores[b * 1024 + sbase + i * 16 + q * 4 + r], rsum[i][r]);
  }
}

// ---------------- K2 fallback: fp32-input energy GEMM (round-1 version) ----------------------
__global__ __launch_bounds__(256) void energy_kernel(
    const float* __restrict__ enc, const float* __restrict__ attn_W,
    const float* __restrict__ hb, const float* __restrict__ v_W,
    float* __restrict__ scores)
{
  __shared__ short Al[128][40];
  __shared__ short Bl[128][40];
  const int tid = threadIdx.x;
  const int lane = tid & 63, wave = tid >> 6;
  const int m0 = blockIdx.x * 128;
  const int n0 = blockIdx.y * 128;
  const int b  = m0 >> 10;
  const int wm = (wave >> 1) * 64, wn = (wave & 1) * 64;

  f32x4 acc[4][4];
  #pragma unroll
  for (int i = 0; i < 4; ++i)
    #pragma unroll
    for (int j = 0; j < 4; ++j) acc[i][j] = (f32x4){0.f, 0.f, 0.f, 0.f};

  const int srow = tid >> 1;
  const int scol = (tid & 1) * 16;
  const float* aptr = enc    + (size_t)(m0 + srow) * 2048 + scol;
  const float* bptr = attn_W + (size_t)(n0 + srow) * 3072 + 1024 + scol;
  const int fl = lane & 15, fq = (lane >> 4) * 8;

  for (int k0 = 0; k0 < 2048; k0 += 32) {
    const float4* a4 = (const float4*)(aptr + k0);
    float4 fa0 = a4[0], fa1 = a4[1], fa2 = a4[2], fa3 = a4[3];
    const float4* b4 = (const float4*)(bptr + k0);
    float4 fb0 = b4[0], fb1 = b4[1], fb2 = b4[2], fb3 = b4[3];
    *(uint4*)&Al[srow][scol]     = pack8(fa0, fa1);
    *(uint4*)&Al[srow][scol + 8] = pack8(fa2, fa3);
    *(uint4*)&Bl[srow][scol]     = pack8(fb0, fb1);
    *(uint4*)&Bl[srow][scol + 8] = pack8(fb2, fb3);
    __syncthreads();
    bf16x8 af[4], bf[4];
    #pragma unroll
    for (int i = 0; i < 4; ++i) af[i] = *(const bf16x8*)&Al[wm + i * 16 + fl][fq];
    #pragma unroll
    for (int j = 0; j < 4; ++j) bf[j] = *(const bf16x8*)&Bl[wn + j * 16 + fl][fq];
    #pragma unroll
    for (int i = 0; i < 4; ++i)
      #pragma unroll
      for (int j = 0; j < 4; ++j)
        acc[i][j] = __builtin_amdgcn_mfma_f32_16x16x32_bf16(af[i], bf[j], acc[i][j], 0, 0, 0);
    __syncthreads();
  }

  float rsum[4][4];
  #pragma unroll
  for (int i = 0; i < 4; ++i)
    #pragma unroll
    for (int r = 0; r < 4; ++r) rsum[i][r] = 0.f;
  const int col_base = n0 + wn + (lane & 15);
  #pragma unroll
  for (int j = 0; j < 4; ++j) {
    int col = col_base + j * 16;
    float hbv = hb[b * 1024 + col];
    float vv  = v_W[col];
    #pragma unroll
    for (int i = 0; i < 4; ++i)
      #pragma unroll
      for (int r = 0; r < 4; ++r)
        rsum[i][r] += vv * tanhf(acc[i][j][r] + hbv);
  }
  #pragma unroll
  for (int i = 0; i < 4; ++i)
    #pragma unroll
    for (int r = 0; r < 4; ++r) {
      float v = rsum[i][r];
      v += __shfl_xor(v, 1); v += __shfl_xor(v, 2);
      v += __shfl_xor(v, 4); v += __shfl_xor(v, 8);
      rsum[i][r] = v;
    }
  if ((lane & 15) == 0) {
    const int q = lane >> 4;
    const int sbase = (m0 & 1023) + wm;
    #pragma unroll
    for (int i = 0; i < 4; ++i)
      #pragma unroll
      for (int r = 0; r < 4; ++r)
        atomicAdd(&scores[b * 1024 + sbase + i * 16 + q * 4 + r], rsum[i][r]);
  }
}

// ---------------- K3: softmax over S per b -> weights (into d_out) ----------------------------
__global__ __launch_bounds__(256) void softmax_kernel(
    const float* __restrict__ scores, float* __restrict__ wout)
{
  __shared__ float red[8];
  const int b = blockIdx.x, tid = threadIdx.x;
  const int lane = tid & 63, wave = tid >> 6;
  float v[4];
  #pragma unroll
  for (int r = 0; r < 4; ++r) v[r] = scores[b * 1024 + r * 256 + tid];
  float m = fmaxf(fmaxf(v[0], v[1]), fmaxf(v[2], v[3]));
  #pragma unroll
  for (int d = 1; d < 64; d <<= 1) m = fmaxf(m, __shfl_xor(m, d));
  if (lane == 0) red[wave] = m;
  __syncthreads();
  float M = fmaxf(fmaxf(red[0], red[1]), fmaxf(red[2], red[3]));
  float s = 0.f;
  #pragma unroll
  for (int r = 0; r < 4; ++r) { v[r] = expf(v[r] - M); s += v[r]; }
  #pragma unroll
  for (int d = 1; d < 64; d <<= 1) s += __shfl_xor(s, d);
  __syncthreads();
  if (lane == 0) red[4 + wave] = s;
  __syncthreads();
  float inv = 1.f / (red[4] + red[5] + red[6] + red[7]);
  #pragma unroll
  for (int r = 0; r < 4; ++r) wout[b * 1024 + r * 256 + tid] = v[r] * inv;
}

// ---------------- K4 fast: context from bf16 enc, s-split + atomics ---------------------------
// grid (8, 32): blockIdx.x = s-chunk of 128, blockIdx.y = b. Thread handles 8 cols (uint4).
__global__ __launch_bounds__(256) void context2_kernel(
    const short* __restrict__ Ac, const float* __restrict__ wts, float* __restrict__ lstm_in)
{
  __shared__ float wl[128];
  const int tid = threadIdx.x;
  const int b = blockIdx.y;
  const int s0 = blockIdx.x * 128;
  if (tid < 128) wl[tid] = wts[b * 1024 + s0 + tid];
  __syncthreads();
  const short* ep = Ac + (size_t)b * (1024 * 2048) + (size_t)s0 * 2048 + tid * 8;
  float a[8];
  #pragma unroll
  for (int j = 0; j < 8; ++j) a[j] = 0.f;
  for (int s = 0; s < 128; ++s) {
    uint4 v = *(const uint4*)(ep + (size_t)s * 2048);
    float w = wl[s];
    a[0] += w * __uint_as_float(v.x << 16);
    a[1] += w * __uint_as_float(v.x & 0xffff0000u);
    a[2] += w * __uint_as_float(v.y << 16);
    a[3] += w * __uint_as_float(v.y & 0xffff0000u);
    a[4] += w * __uint_as_float(v.z << 16);
    a[5] += w * __uint_as_float(v.z & 0xffff0000u);
    a[6] += w * __uint_as_float(v.w << 16);
    a[7] += w * __uint_as_float(v.w & 0xffff0000u);
  }
  float* dst = lstm_in + b * 2560 + 512 + tid * 8;
  #pragma unroll
  for (int j = 0; j < 8; ++j) atomicAdd(&dst[j], a[j]);
}

// ---------------- K4 fallback: fp32 context ---------------------------------------------------
__global__ __launch_bounds__(256) void context_kernel(
    const float* __restrict__ enc, const float* __restrict__ wts, float* __restrict__ lstm_in)
{
  __shared__ float wl[1024];
  const int tid = threadIdx.x;
  const int b = blockIdx.y;
  const int col = blockIdx.x * 256 + tid;
  #pragma unroll
  for (int r = 0; r < 4; ++r) wl[r * 256 + tid] = wts[b * 1024 + r * 256 + tid];
  __syncthreads();
  const float* ep = enc + (size_t)b * (1024 * 2048) + col;
  float a0 = 0.f, a1 = 0.f, a2 = 0.f, a3 = 0.f;
  for (int s = 0; s < 1024; s += 8) {
    a0 += wl[s + 0] * ep[(size_t)(s + 0) * 2048];
    a1 += wl[s + 1] * ep[(size_t)(s + 1) * 2048];
    a2 += wl[s + 2] * ep[(size_t)(s + 2) * 2048];
    a3 += wl[s + 3] * ep[(size_t)(s + 3) * 2048];
    a0 += wl[s + 4] * ep[(size_t)(s + 4) * 2048];
    a1 += wl[s + 5] * ep[(size_t)(s + 5) * 2048];
    a2 += wl[s + 6] * ep[(size_t)(s + 6) * 2048];
    a3 += wl[s + 7] * ep[(size_t)(s + 7) * 2048];
  }
  lstm_in[b * 2560 + 512 + col] = (a0 + a1) + (a2 + a3);
}

// ---------------- skinny GEMM: out[b][j] += sum_{k chunk} W[j][k]*X[b][k], B=32 ---------------
__global__ __launch_bounds__(256) void skinny_gemm(
    const float* __restrict__ W, const float* __restrict__ X, float* __restrict__ out,
    int K, int Kc, int ldx, int ldo)
{
  __shared__ float Wl[256][33];
  const int tid = threadIdx.x;
  const int j0 = blockIdx.x * 256;
  const int k0 = blockIdx.y * Kc;
  float acc[32];
  #pragma unroll
  for (int b = 0; b < 32; ++b) acc[b] = 0.f;

  for (int kc = k0; kc < k0 + Kc; kc += 32) {
    __syncthreads();
    #pragma unroll
    for (int q = 0; q < 8; ++q) {
      int row = q * 32 + (tid >> 3);
      int col = (tid & 7) * 4;
      float4 v = *(const float4*)(W + (size_t)(j0 + row) * K + kc + col);
      Wl[row][col + 0] = v.x; Wl[row][col + 1] = v.y;
      Wl[row][col + 2] = v.z; Wl[row][col + 3] = v.w;
    }
    __syncthreads();
    float wreg[32];
    #pragma unroll
    for (int q = 0; q < 32; ++q) wreg[q] = Wl[tid][q];
    #pragma unroll
    for (int b = 0; b < 32; ++b) {
      const float* xp = X + b * ldx + kc;   // wave-uniform -> scalar loads
      float s = 0.f;
      #pragma unroll
      for (int q = 0; q < 32; ++q) s += wreg[q] * xp[q];
      acc[b] += s;
    }
  }
  const int j = j0 + tid;
  #pragma unroll
  for (int b = 0; b < 32; ++b) atomicAdd(&out[(size_t)b * ldo + j], acc[b]);
}

// ---------------- K6: LSTM cell elementwise --------------------------------------------------
__global__ __launch_bounds__(256) void cell_kernel(
    const float* __restrict__ gates, const float* __restrict__ cell_in,
    float* __restrict__ out_h, float* __restrict__ out_c)
{
  const int idx = blockIdx.x * 256 + threadIdx.x;
  const int b = idx >> 10, h = idx & 1023;
  const float* g = gates + b * 4096;
  float ig = g[h], fg = g[1024 + h], gg = g[2048 + h], og = g[3072 + h];
  float c = cell_in[idx];
  float si = 1.f / (1.f + expf(-ig));
  float sf = 1.f / (1.f + expf(-fg));
  float so = 1.f / (1.f + expf(-og));
  float cn = sf * c + si * tanhf(gg);
  float hn = so * tanhf(cn);
  out_c[idx] = cn;
  out_h[idx] = hn;
}

extern "C" void kernel_launch(void* const* d_in, const int* in_sizes, int n_in,
                              void* d_out, int out_size, void* d_ws, size_t ws_size,
                              hipStream_t stream) {
  const int*   x       = (const int*)  d_in[0];
  const float* hidden  = (const float*)d_in[1];
  const float* cell    = (const float*)d_in[2];
  const float* enc     = (const float*)d_in[3];
  const float* emb     = (const float*)d_in[4];
  const float* attn_W  = (const float*)d_in[5];
  const float* attn_b  = (const float*)d_in[6];
  const float* v_W     = (const float*)d_in[7];
  const float* W_ih    = (const float*)d_in[8];
  const float* W_hh    = (const float*)d_in[9];
  const float* b_ih    = (const float*)d_in[10];
  const float* b_hh    = (const float*)d_in[11];
  const float* fc_W    = (const float*)d_in[12];
  const float* fc_b    = (const float*)d_in[13];

  float* out   = (float*)d_out;
  float* pred  = out;
  float* out_h = out + 1024000;
  float* out_c = out + 1056768;
  float* out_w = out + 1089536;

  float* ws      = (float*)d_ws;
  float* scores  = ws;                 // 32768
  float* hb      = ws + 32768;         // 32768
  float* lstm_in = ws + 65536;         // 32*2560
  float* gates   = ws + 147456;       // 32*4096
  // bf16 region at byte offset 1114112 (16B aligned)
  short* Ac = (short*)((char*)d_ws + 1114112);          // 32768*2048 bf16 = 128 MB
  short* Bc = Ac + (size_t)32768 * 2048;                // 1024*2048 bf16 = 4 MB
  const size_t need = 1114112 + (size_t)32768 * 2048 * 2 + (size_t)1024 * 2048 * 2;
  const bool fast = ws_size >= need;

  init_kernel<<<4960, 256, 0, stream>>>(scores, gates, pred, lstm_in, x, emb, b_ih, b_hh, fc_b);
  hb_kernel<<<256, 256, 0, stream>>>(hidden, attn_W, attn_b, hb);
  if (fast) {
    convert_kernel<<<33792, 256, 0, stream>>>(enc, attn_W, Ac, Bc);
    energy2_kernel<<<dim3(256, 8), 256, 0, stream>>>(Ac, Bc, hb, v_W, scores);
    softmax_kernel<<<32, 256, 0, stream>>>(scores, out_w);
    context2_kernel<<<dim3(8, 32), 256, 0, stream>>>(Ac, out_w, lstm_in);
  } else {
    energy_kernel<<<dim3(256, 8), 256, 0, stream>>>(enc, attn_W, hb, v_W, scores);
    softmax_kernel<<<32, 256, 0, stream>>>(scores, out_w);
    context_kernel<<<dim3(8, 32), 256, 0, stream>>>(enc, out_w, lstm_in);
  }
  skinny_gemm<<<dim3(16, 16), 256, 0, stream>>>(W_ih, lstm_in, gates, 2560, 160, 2560, 4096);
  skinny_gemm<<<dim3(16, 8), 256, 0, stream>>>(W_hh, hidden, gates, 1024, 128, 1024, 4096);
  cell_kernel<<<128, 256, 0, stream>>>(gates, cell, out_h, out_c);
  skinny_gemm<<<dim3(125, 2), 256, 0, stream>>>(fc_W, out_h, pred, 1024, 512, 1024, 32000);
}